// Round 1
// baseline (392.667 us; speedup 1.0000x reference)
//
#include <hip/hip_runtime.h>
#include <hip/hip_bf16.h>
#include <stdint.h>

// Problem constants (fixed by setup_inputs)
#define M_N  16384   // batch rows
#define K_C  2048    // centers
#define DIM  512     // feature dim
#define NCLS 10      // classes

typedef unsigned short u16;
typedef float  f32x4  __attribute__((ext_vector_type(4)));
typedef __bf16 bf16x8 __attribute__((ext_vector_type(8)));

// ---- helpers -------------------------------------------------------------

__device__ __forceinline__ void async_ld16(const void* g, void* l) {
  // global -> LDS direct DMA, 16 bytes per lane. LDS dest must be
  // wave-uniform base + lane*16 (it is: lds off is linear in tid).
  __builtin_amdgcn_global_load_lds(
      (const __attribute__((address_space(1))) void*)g,
      (__attribute__((address_space(3))) void*)l,
      16, 0, 0);
}

__device__ __forceinline__ u16 f2bf_rne(float f) {
  // round-to-nearest-even fp32 -> bf16 (inputs are finite, no NaN handling)
  uint32_t u = __float_as_uint(f);
  u += 0x7FFFu + ((u >> 16) & 1u);
  return (u16)(u >> 16);
}

// ---- kernel 0: out[i][j] = b[j] (atomic accumulation target) -------------

__global__ void init_out(float* __restrict__ out, const float* __restrict__ b) {
  int i = blockIdx.x * 256 + threadIdx.x;
  if (i < M_N * NCLS) out[i] = b[i % NCLS];
}

// ---- kernel 1: fp32 [R][512] -> bf16 [R][512] + row sum-of-squares -------

__global__ void convert_rows(const float4* __restrict__ src,
                             ushort4* __restrict__ dst,
                             float* __restrict__ sq) {
  int row = blockIdx.x;
  int t = threadIdx.x;                       // 128 threads, 4 floats each
  float4 v = src[(size_t)row * 128 + t];
  float ss = v.x * v.x + v.y * v.y + v.z * v.z + v.w * v.w;
  ushort4 o;
  o.x = f2bf_rne(v.x); o.y = f2bf_rne(v.y);
  o.z = f2bf_rne(v.z); o.w = f2bf_rne(v.w);
  dst[(size_t)row * 128 + t] = o;
  ss += __shfl_down(ss, 32);
  ss += __shfl_down(ss, 16);
  ss += __shfl_down(ss, 8);
  ss += __shfl_down(ss, 4);
  ss += __shfl_down(ss, 2);
  ss += __shfl_down(ss, 1);
  __shared__ float part[2];
  if ((t & 63) == 0) part[t >> 6] = ss;
  __syncthreads();
  if (t == 0) sq[row] = part[0] + part[1];
}

// ---- kernel 2: fused  xc-GEMM -> radial -> (radial @ W^T) atomics --------
// grid = (K_C/128, M_N/128), block = 256 (4 waves, 2x2 of 64x64)

__global__ __launch_bounds__(256, 2) void rbf_main(
    const u16* __restrict__ A,      // bf16 bits [M_N][DIM]
    const u16* __restrict__ B,      // bf16 bits [K_C][DIM]
    const float* __restrict__ x2,   // [M_N]
    const float* __restrict__ c2,   // [K_C]
    const float* __restrict__ beta, // [K_C]
    const float* __restrict__ W,    // [NCLS][K_C]
    float* __restrict__ out) {      // [M_N][NCLS]
  constexpr int BM = 128, BN = 128, BK = 32;
  constexpr int RLD = BM + 4;  // radial LDS row stride (u16), +4 breaks banks
  // union: [0,8K) A-tile + [8K,16K) B-tile during K-loop; radial_t after.
  __shared__ alignas(16) unsigned char smem[BN * RLD * 2];  // 33792 B
  u16* As = (u16*)smem;          // [BM][BK]
  u16* Bs = (u16*)(smem + 8192); // [BN][BK]
  u16* Rt = (u16*)smem;          // [BN][RLD] transposed radial (bf16)

  const int tid  = threadIdx.x;
  const int lane = tid & 63;
  const int wid  = tid >> 6;
  const int bn = blockIdx.x, bm = blockIdx.y;
  const int row0 = bm * BM, col0 = bn * BN;
  const int wr = (wid >> 1) * 64;   // wave row offset in tile
  const int wc = (wid & 1) * 64;    // wave col offset in tile

  f32x4 acc[4][4] = {};

  // staging addresses: thread t covers row t>>2, 8-elem k-chunk (t&3)
  const int srow = tid >> 2;
  const int scol = (tid & 3) * 8;
  const u16* aG = A + (size_t)(row0 + srow) * DIM + scol;
  const u16* bG = B + (size_t)(col0 + srow) * DIM + scol;
  u16* aL = As + tid * 8;   // byte off = tid*16: wave-uniform base + lane*16
  u16* bL = Bs + tid * 8;

  const int frow = lane & 15;        // MFMA A/B operand row (m or n)
  const int fko  = (lane >> 4) * 8;  // MFMA k-group offset

  for (int k0 = 0; k0 < DIM; k0 += BK) {
    __syncthreads();  // previous iter's ds_reads done before overwrite
    async_ld16(aG + k0,            aL);
    async_ld16(aG + k0 + 64 * DIM, aL + 64 * BK);
    async_ld16(bG + k0,            bL);
    async_ld16(bG + k0 + 64 * DIM, bL + 64 * BK);
    __syncthreads();  // compiler drains vmcnt before s_barrier -> tiles ready

    bf16x8 af[4], bfr[4];
#pragma unroll
    for (int mi = 0; mi < 4; ++mi)
      af[mi] = *(const bf16x8*)(As + (wr + mi * 16 + frow) * BK + fko);
#pragma unroll
    for (int ni = 0; ni < 4; ++ni)
      bfr[ni] = *(const bf16x8*)(Bs + (wc + ni * 16 + frow) * BK + fko);
#pragma unroll
    for (int mi = 0; mi < 4; ++mi)
#pragma unroll
      for (int ni = 0; ni < 4; ++ni)
        acc[mi][ni] = __builtin_amdgcn_mfma_f32_16x16x32_bf16(
            af[mi], bfr[ni], acc[mi][ni], 0, 0, 0);
  }

  // ---- epilogue: radial = exp(-beta*sqrt(max(x2+c2-2xc,0))) ----
  // C/D layout (16x16x32): col = lane&15, row = (lane>>4)*4 + reg
  float c2v[4], btv[4];
#pragma unroll
  for (int ni = 0; ni < 4; ++ni) {
    int gc = col0 + wc + ni * 16 + (lane & 15);
    c2v[ni] = c2[gc];
    btv[ni] = beta[gc];
  }
  float x2v[4][4];
#pragma unroll
  for (int mi = 0; mi < 4; ++mi)
#pragma unroll
    for (int r = 0; r < 4; ++r)
      x2v[mi][r] = x2[row0 + wr + mi * 16 + (lane >> 4) * 4 + r];

  __syncthreads();  // K-loop LDS use finished; smem becomes Rt

  union Pack { u16 h[4]; uint2 v; };
#pragma unroll
  for (int mi = 0; mi < 4; ++mi) {
#pragma unroll
    for (int ni = 0; ni < 4; ++ni) {
      Pack pk;
#pragma unroll
      for (int r = 0; r < 4; ++r) {
        float xc = acc[mi][ni][r];
        float d2 = fmaxf(x2v[mi][r] + c2v[ni] - 2.0f * xc, 0.0f);
        float radial = __expf(-btv[ni] * sqrtf(d2));
        pk.h[r] = f2bf_rne(radial);
      }
      int ccol = wc + ni * 16 + (lane & 15);
      int rrow = wr + mi * 16 + (lane >> 4) * 4;  // 4 consecutive rows
      *(uint2*)(Rt + ccol * RLD + rrow) = pk.v;   // 8B store, 8B aligned
    }
  }
  __syncthreads();

  // ---- reduce over this block's 128 centers into out (atomic) ----
  // tid = [jh(1)][ch(1)][lane(6)]: rows 2*lane,2*lane+1; col half ch; j half jh
  const int r2 = (tid & 63) * 2;
  const int ch = (tid >> 6) & 1;   // wave-uniform
  const int jh = (tid >> 7) & 1;   // wave-uniform
  float accj[2][5] = {};
  for (int ci = 0; ci < 64; ++ci) {
    int c = ch * 64 + ci;
    uint32_t pr = *(const uint32_t*)(Rt + c * RLD + r2);  // rows r2, r2+1
    float v0 = __uint_as_float(pr << 16);
    float v1 = __uint_as_float(pr & 0xFFFF0000u);
    int gc = col0 + c;               // wave-uniform -> scalar loads of W
#pragma unroll
    for (int jj = 0; jj < 5; ++jj) {
      float w = W[(jh * 5 + jj) * K_C + gc];
      accj[0][jj] += v0 * w;
      accj[1][jj] += v1 * w;
    }
  }
#pragma unroll
  for (int rr = 0; rr < 2; ++rr)
#pragma unroll
    for (int jj = 0; jj < 5; ++jj)
      atomicAdd(&out[(size_t)(row0 + r2 + rr) * NCLS + jh * 5 + jj],
                accj[rr][jj]);
}

// ---- launch --------------------------------------------------------------

extern "C" void kernel_launch(void* const* d_in, const int* in_sizes, int n_in,
                              void* d_out, int out_size, void* d_ws, size_t ws_size,
                              hipStream_t stream) {
  const float* batches = (const float*)d_in[0];  // [16384,512]
  const float* centers = (const float*)d_in[1];  // [2048,512]
  const float* beta    = (const float*)d_in[2];  // [1,2048]
  const float* W       = (const float*)d_in[3];  // [10,2048]
  const float* bias    = (const float*)d_in[4];  // [10]
  float* out = (float*)d_out;                    // [16384,10]

  char* ws = (char*)d_ws;
  u16*  Abf = (u16*)ws;                                       // 16 MiB
  u16*  Bbf = (u16*)(ws + (size_t)M_N * DIM * 2);             // 2 MiB
  float* x2 = (float*)(ws + (size_t)M_N * DIM * 2 + (size_t)K_C * DIM * 2);
  float* c2 = x2 + M_N;

  init_out<<<dim3((M_N * NCLS + 255) / 256), dim3(256), 0, stream>>>(out, bias);
  convert_rows<<<dim3(M_N), dim3(128), 0, stream>>>(
      (const float4*)batches, (ushort4*)Abf, x2);
  convert_rows<<<dim3(K_C), dim3(128), 0, stream>>>(
      (const float4*)centers, (ushort4*)Bbf, c2);
  rbf_main<<<dim3(K_C / 128, M_N / 128), dim3(256), 0, stream>>>(
      Abf, Bbf, x2, c2, beta, W, out);
}

// Round 2
// 163.199 us; speedup vs baseline: 2.4061x; 2.4061x over previous
//
#include <hip/hip_runtime.h>
#include <hip/hip_bf16.h>
#include <stdint.h>

// Problem constants (fixed by setup_inputs)
#define M_N  16384   // batch rows
#define K_C  2048    // centers
#define DIM  512     // feature dim
#define NCLS 10      // classes
#define NBN  (K_C / 128)   // 16 center-blocks -> partial slices

typedef unsigned short u16;
typedef float  f32x4  __attribute__((ext_vector_type(4)));
typedef __bf16 bf16x8 __attribute__((ext_vector_type(8)));

// ---- helpers -------------------------------------------------------------

__device__ __forceinline__ void async_ld16(const void* g, void* l) {
  // global -> LDS direct DMA, 16 bytes per lane. LDS dest must be
  // wave-uniform base + lane*16 (it is: lds off is linear in tid).
  __builtin_amdgcn_global_load_lds(
      (const __attribute__((address_space(1))) void*)g,
      (__attribute__((address_space(3))) void*)l,
      16, 0, 0);
}

__device__ __forceinline__ u16 f2bf_rne(float f) {
  uint32_t u = __float_as_uint(f);
  u += 0x7FFFu + ((u >> 16) & 1u);
  return (u16)(u >> 16);
}

// ---- kernel 1: fp32 [R][512] -> bf16 [R][512] + row sum-of-squares -------

__global__ void convert_rows(const float4* __restrict__ src,
                             ushort4* __restrict__ dst,
                             float* __restrict__ sq) {
  int row = blockIdx.x;
  int t = threadIdx.x;                       // 128 threads, 4 floats each
  float4 v = src[(size_t)row * 128 + t];
  float ss = v.x * v.x + v.y * v.y + v.z * v.z + v.w * v.w;
  ushort4 o;
  o.x = f2bf_rne(v.x); o.y = f2bf_rne(v.y);
  o.z = f2bf_rne(v.z); o.w = f2bf_rne(v.w);
  dst[(size_t)row * 128 + t] = o;
  ss += __shfl_down(ss, 32);
  ss += __shfl_down(ss, 16);
  ss += __shfl_down(ss, 8);
  ss += __shfl_down(ss, 4);
  ss += __shfl_down(ss, 2);
  ss += __shfl_down(ss, 1);
  __shared__ float part[2];
  if ((t & 63) == 0) part[t >> 6] = ss;
  __syncthreads();
  if (t == 0) sq[row] = part[0] + part[1];
}

// ---- kernel 2: fused  xc-GEMM -> radial -> partial (radial @ W^T) --------
// grid = (NBN, M_N/128), block = 256 (4 waves, 2x2 of 64x64). BK=64.

__global__ __launch_bounds__(256, 2) void rbf_main(
    const u16* __restrict__ A,      // bf16 bits [M_N][DIM]
    const u16* __restrict__ B,      // bf16 bits [K_C][DIM]
    const float* __restrict__ x2,   // [M_N]
    const float* __restrict__ c2,   // [K_C]
    const float* __restrict__ beta, // [K_C]
    const float* __restrict__ W,    // [NCLS][K_C]
    float* __restrict__ partial) {  // [NBN][M_N][NCLS]
  constexpr int BM = 128, BK = 64;
  constexpr int RLD = BM + 4;  // radial LDS row stride (u16), +4 breaks banks
  // union: [0,16K) A-tile + [16K,32K) B-tile during K-loop; radial_t after.
  __shared__ alignas(16) unsigned char smem[128 * RLD * 2];  // 33792 B
  u16* As = (u16*)smem;           // [BM][BK]
  u16* Bs = (u16*)(smem + 16384); // [BN][BK]
  u16* Rt = (u16*)smem;           // [BN][RLD] transposed radial (bf16)

  const int tid  = threadIdx.x;
  const int lane = tid & 63;
  const int wid  = tid >> 6;
  const int bn = blockIdx.x, bm = blockIdx.y;
  const int row0 = bm * BM, col0 = bn * 128;
  const int wr = (wid >> 1) * 64;   // wave row offset in tile
  const int wc = (wid & 1) * 64;    // wave col offset in tile

  f32x4 acc[4][4] = {};

  // staging: thread t covers row t>>3 (+32*i), 8-elem k-chunk (t&7)
  const int srow = tid >> 3;
  const int scol = (tid & 7) * 8;
  const u16* aG = A + (size_t)(row0 + srow) * DIM + scol;
  const u16* bG = B + (size_t)(col0 + srow) * DIM + scol;
  u16* aL = As + tid * 8;   // byte off = tid*16: wave-uniform base + lane*16
  u16* bL = Bs + tid * 8;

  const int frow = lane & 15;        // MFMA A/B operand row (m or n)
  const int fko  = (lane >> 4) * 8;  // MFMA k-group offset

  for (int k0 = 0; k0 < DIM; k0 += BK) {
    __syncthreads();  // previous iter's ds_reads done before overwrite
#pragma unroll
    for (int i = 0; i < 4; ++i) {
      async_ld16(aG + k0 + i * 32 * DIM, aL + i * 2048);
      async_ld16(bG + k0 + i * 32 * DIM, bL + i * 2048);
    }
    __syncthreads();  // vmcnt drained before s_barrier -> tiles ready

#pragma unroll
    for (int kh = 0; kh < 2; ++kh) {
      bf16x8 af[4], bfr[4];
#pragma unroll
      for (int mi = 0; mi < 4; ++mi)
        af[mi] = *(const bf16x8*)(As + (wr + mi * 16 + frow) * BK + kh * 32 + fko);
#pragma unroll
      for (int ni = 0; ni < 4; ++ni)
        bfr[ni] = *(const bf16x8*)(Bs + (wc + ni * 16 + frow) * BK + kh * 32 + fko);
#pragma unroll
      for (int mi = 0; mi < 4; ++mi)
#pragma unroll
        for (int ni = 0; ni < 4; ++ni)
          acc[mi][ni] = __builtin_amdgcn_mfma_f32_16x16x32_bf16(
              af[mi], bfr[ni], acc[mi][ni], 0, 0, 0);
    }
  }

  // ---- epilogue: radial = exp(-beta*sqrt(max(x2+c2-2xc,0))) ----
  // C/D layout (16x16x32): col = lane&15, row = (lane>>4)*4 + reg
  float c2v[4], btv[4];
#pragma unroll
  for (int ni = 0; ni < 4; ++ni) {
    int gc = col0 + wc + ni * 16 + (lane & 15);
    c2v[ni] = c2[gc];
    btv[ni] = beta[gc];
  }
  float x2v[4][4];
#pragma unroll
  for (int mi = 0; mi < 4; ++mi)
#pragma unroll
    for (int r = 0; r < 4; ++r)
      x2v[mi][r] = x2[row0 + wr + mi * 16 + (lane >> 4) * 4 + r];

  __syncthreads();  // K-loop LDS use finished; smem becomes Rt

  union Pack { u16 h[4]; uint2 v; };
#pragma unroll
  for (int mi = 0; mi < 4; ++mi) {
#pragma unroll
    for (int ni = 0; ni < 4; ++ni) {
      Pack pk;
#pragma unroll
      for (int r = 0; r < 4; ++r) {
        float xc = acc[mi][ni][r];
        float d2 = fmaxf(x2v[mi][r] + c2v[ni] - 2.0f * xc, 0.0f);
        float radial = __expf(-btv[ni] * sqrtf(d2));
        pk.h[r] = f2bf_rne(radial);
      }
      int ccol = wc + ni * 16 + (lane & 15);
      int rrow = wr + mi * 16 + (lane >> 4) * 4;  // 4 consecutive rows
      *(uint2*)(Rt + ccol * RLD + rrow) = pk.v;   // 8B store, 8B aligned
    }
  }
  __syncthreads();

  // ---- reduce this block's 128 centers -> partial[bn] (plain stores) ----
  // thread t: row r = t&127, class-half jh = t>>7 (5 classes each)
  const int r  = tid & 127;
  const int jh = tid >> 7;   // wave-uniform
  float accj[5] = {};
  for (int c = 0; c < 128; ++c) {
    uint32_t bits = (uint32_t)Rt[c * RLD + r];
    float v = __uint_as_float(bits << 16);
    int gc = col0 + c;               // wave-uniform -> scalar loads of W
#pragma unroll
    for (int jj = 0; jj < 5; ++jj)
      accj[jj] += v * W[(jh * 5 + jj) * K_C + gc];
  }
  float* dst = partial + (size_t)bn * (M_N * NCLS)
             + (size_t)(row0 + r) * NCLS + jh * 5;
#pragma unroll
  for (int jj = 0; jj < 5; ++jj) dst[jj] = accj[jj];
}

// ---- kernel 3: out[i][j] = b[j] + sum_bn partial[bn][i][j] ---------------

__global__ void reduce_out(const float* __restrict__ partial,
                           const float* __restrict__ b,
                           float* __restrict__ out) {
  int idx = blockIdx.x * 256 + threadIdx.x;
  if (idx >= M_N * NCLS) return;
  float s = b[idx % NCLS];
#pragma unroll
  for (int bn = 0; bn < NBN; ++bn)
    s += partial[(size_t)bn * (M_N * NCLS) + idx];
  out[idx] = s;
}

// ---- launch --------------------------------------------------------------

extern "C" void kernel_launch(void* const* d_in, const int* in_sizes, int n_in,
                              void* d_out, int out_size, void* d_ws, size_t ws_size,
                              hipStream_t stream) {
  const float* batches = (const float*)d_in[0];  // [16384,512]
  const float* centers = (const float*)d_in[1];  // [2048,512]
  const float* beta    = (const float*)d_in[2];  // [1,2048]
  const float* W       = (const float*)d_in[3];  // [10,2048]
  const float* bias    = (const float*)d_in[4];  // [10]
  float* out = (float*)d_out;                    // [16384,10]

  char* ws = (char*)d_ws;
  u16*  Abf = (u16*)ws;                                       // 16 MiB
  u16*  Bbf = (u16*)(ws + (size_t)M_N * DIM * 2);             // 2 MiB
  float* x2 = (float*)(ws + (size_t)M_N * DIM * 2 + (size_t)K_C * DIM * 2);
  float* c2 = x2 + M_N;
  float* partial = c2 + K_C;                                  // 10.5 MiB

  convert_rows<<<dim3(M_N), dim3(128), 0, stream>>>(
      (const float4*)batches, (ushort4*)Abf, x2);
  convert_rows<<<dim3(K_C), dim3(128), 0, stream>>>(
      (const float4*)centers, (ushort4*)Bbf, c2);
  rbf_main<<<dim3(NBN, M_N / 128), dim3(256), 0, stream>>>(
      Abf, Bbf, x2, c2, beta, W, partial);
  reduce_out<<<dim3((M_N * NCLS + 255) / 256), dim3(256), 0, stream>>>(
      partial, bias, out);
}